// Round 6
// baseline (294.324 us; speedup 1.0000x reference)
//
#include <hip/hip_runtime.h>
#include <math.h>

// NoisyTopkRouter: B=4,S=4096,D=2048,E=64,TOP_K=8
// fp32 fused GEMM + epilogue; tokens whose top-9 noisy-logit gaps are < TAU
// are re-computed exactly in fp64 (ordering then matches the np reference).

#define BM 32
#define BK 32
#define NTHREADS 256
#define KDIM 2048
#define NEXP 64
#define LDA 36
#define LDB 132
#define LDSC 129
#define NCHUNK (KDIM / BK)
#define TAU 1e-4f

union alignas(16) SMem {
  struct {                    // GEMM phase
    float As[2][BK][LDA];
    float Bs[2][BK][LDB];
  } t;
  float sc[BM][LDSC];         // epilogue phase (aliases t)
  struct {                    // fp64 refine phase (aliases both, both dead)
    float  xls[KDIM];         // 8 KB   x row
    double part[128][2];      // 2 KB   half-dots
    double nv64[NEXP];        // 512 B  refined noisy logits
    double pe64[NEXP];        // 512 B  exp(nv - m)
  } r;
};

__global__ __launch_bounds__(NTHREADS, 2)
void noisy_topk_router(const float* __restrict__ x,
                       const float* __restrict__ Wr,
                       const float* __restrict__ br,
                       const float* __restrict__ Wn,
                       const float* __restrict__ bn,
                       const float* __restrict__ noise,
                       float* __restrict__ out_w,
                       float* __restrict__ out_i,
                       float* __restrict__ out_s)
{
  __shared__ SMem sm;
  __shared__ int    flagcnt;
  __shared__ int    flaglist[BM];
  __shared__ double m64s;

  const int tid  = threadIdx.x;
  const int row0 = blockIdx.x * BM;
  if (tid == 0) flagcnt = 0;

  // ---------------- fp32 GEMM (proven in round 1) ----------------
  const int t_a = tid >> 3;
  const int k4  = (tid & 7) << 2;
  const int e_b = tid >> 3;
  const int tg  = tid >> 5;
  const int og  = tid & 31;

  const float* xrow = x + (size_t)(row0 + t_a) * KDIM + k4;
  const float* wrow[4];
#pragma unroll
  for (int l = 0; l < 4; ++l) {
    const int e = e_b + 32 * l;
    wrow[l] = ((e < NEXP) ? (Wr + (size_t)e * KDIM)
                          : (Wn + (size_t)(e - NEXP) * KDIM)) + k4;
  }

  float acc[4][4] = {};
  float4 aReg, bReg[4];

  aReg = *(const float4*)(xrow);
#pragma unroll
  for (int l = 0; l < 4; ++l) bReg[l] = *(const float4*)(wrow[l]);
#pragma unroll
  for (int i = 0; i < 4; ++i) sm.t.As[0][k4 + i][t_a] = ((const float*)&aReg)[i];
#pragma unroll
  for (int l = 0; l < 4; ++l) {
    const int e = e_b + 32 * l;
#pragma unroll
    for (int i = 0; i < 4; ++i) sm.t.Bs[0][k4 + i][e] = ((const float*)&bReg[l])[i];
  }

  for (int c = 0; c < NCHUNK; ++c) {
    const int cur = c & 1;
    __syncthreads();
    if (c + 1 < NCHUNK) {
      const int koff = (c + 1) * BK;
      aReg = *(const float4*)(xrow + koff);
#pragma unroll
      for (int l = 0; l < 4; ++l) bReg[l] = *(const float4*)(wrow[l] + koff);
    }
#pragma unroll
    for (int k = 0; k < BK; ++k) {
      const float4 av = *(const float4*)&sm.t.As[cur][k][tg << 2];
      const float4 bv = *(const float4*)&sm.t.Bs[cur][k][og << 2];
      const float a4[4] = {av.x, av.y, av.z, av.w};
      const float b4[4] = {bv.x, bv.y, bv.z, bv.w};
#pragma unroll
      for (int i = 0; i < 4; ++i)
#pragma unroll
        for (int j = 0; j < 4; ++j)
          acc[i][j] = fmaf(a4[i], b4[j], acc[i][j]);
    }
    if (c + 1 < NCHUNK) {
      const int nxt = cur ^ 1;
#pragma unroll
      for (int i = 0; i < 4; ++i) sm.t.As[nxt][k4 + i][t_a] = ((const float*)&aReg)[i];
#pragma unroll
      for (int l = 0; l < 4; ++l) {
        const int e = e_b + 32 * l;
#pragma unroll
        for (int i = 0; i < 4; ++i) sm.t.Bs[nxt][k4 + i][e] = ((const float*)&bReg[l])[i];
      }
    }
  }

  __syncthreads();
#pragma unroll
  for (int i = 0; i < 4; ++i)
#pragma unroll
    for (int j = 0; j < 4; ++j)
      sm.sc[(tg << 2) + i][(og << 2) + j] = acc[i][j];
  __syncthreads();

  // ---------------- fp32 epilogue + near-tie detection ----------------
  if (tid < BM) {
    const int t = tid;
    const int token = row0 + t;
    const float* nrow = noise + (size_t)token * NEXP;

    // noisy logits (overwrite route slots; noise slots e+64 untouched)
    for (int e = 0; e < NEXP; ++e) {
      const float rte = sm.sc[t][e] + br[e];
      const float z   = sm.sc[t][e + NEXP] + bn[e];
      const float sp  = fmaxf(z, 0.f) + log1pf(expf(-fabsf(z)));
      sm.sc[t][e] = rte + nrow[e] * sp;
    }
    // top-9 scan on noisy logits (monotone wrt softmax => same ordering)
    unsigned long long taken = 0ull;
    float vals9[9]; int idx9[9];
#pragma unroll
    for (int p = 0; p < 9; ++p) {
      float best = -INFINITY; int bi = 0;
      for (int e = 0; e < NEXP; ++e) {
        const float v = sm.sc[t][e];
        const bool cnd = (v > best) && (((taken >> e) & 1ull) == 0ull);
        best = cnd ? v : best;
        bi   = cnd ? e : bi;
      }
      taken |= (1ull << bi);
      vals9[p] = best; idx9[p] = bi;
    }
    bool flagged = false;
#pragma unroll
    for (int p = 0; p < 8; ++p) flagged |= (vals9[p] - vals9[p + 1] < TAU);

    if (flagged) {
      const int s = atomicAdd(&flagcnt, 1);
      flaglist[s] = t;
    } else {
      const float m = vals9[0];
      float ssum = 0.f;
      for (int e = 0; e < NEXP; ++e) {
        const float p = expf(sm.sc[t][e] - m);
        sm.sc[t][e] = p;
        ssum += p;
      }
      float* srow = out_s + (size_t)token * NEXP;
      for (int e = 0; e < NEXP; ++e) srow[e] = sm.sc[t][e] / ssum;
      float pt[8]; float wsum = 0.f;
#pragma unroll
      for (int p = 0; p < 8; ++p) { pt[p] = expf(vals9[p] - m); wsum += pt[p]; }
#pragma unroll
      for (int p = 0; p < 8; ++p) {
        out_w[(size_t)token * 8 + p] = pt[p] / wsum;
        out_i[(size_t)token * 8 + p] = (float)idx9[p];
      }
    }
  }
  __syncthreads();

  // ---------------- fp64 exact refine for flagged tokens ----------------
  const int nf = flagcnt;
  for (int i = 0; i < nf; ++i) {
    const int t = flaglist[i];
    const int token = row0 + t;
    __syncthreads();                       // r-region reuse safe
    for (int k = tid * 8; k < KDIM; k += NTHREADS * 8) {
      *(float4*)&sm.r.xls[k]     = *(const float4*)&x[(size_t)token * KDIM + k];
      *(float4*)&sm.r.xls[k + 4] = *(const float4*)&x[(size_t)token * KDIM + k + 4];
    }
    __syncthreads();
    {
      const int e = tid & 127, h = tid >> 7;
      const float* Wrow = ((e < NEXP) ? (Wr + (size_t)e * KDIM)
                                      : (Wn + (size_t)(e - NEXP) * KDIM)) + h * 1024;
      const float* xh = sm.r.xls + h * 1024;
      double a0 = 0, a1 = 0, a2 = 0, a3 = 0;
      for (int k = 0; k < 1024; k += 4) {
        const float4 w4 = *(const float4*)&Wrow[k];
        const float4 x4 = *(const float4*)&xh[k];
        a0 = fma((double)x4.x, (double)w4.x, a0);
        a1 = fma((double)x4.y, (double)w4.y, a1);
        a2 = fma((double)x4.z, (double)w4.z, a2);
        a3 = fma((double)x4.w, (double)w4.w, a3);
      }
      sm.r.part[e][h] = (a0 + a1) + (a2 + a3);
    }
    __syncthreads();
    if (tid < NEXP) {
      const double rte = sm.r.part[tid][0] + sm.r.part[tid][1] + (double)br[tid];
      const double z   = sm.r.part[tid + NEXP][0] + sm.r.part[tid + NEXP][1] + (double)bn[tid];
      const double sp  = fmax(z, 0.0) + log1p(exp(-fabs(z)));
      sm.r.nv64[tid] = rte + (double)noise[(size_t)token * NEXP + tid] * sp;
    }
    __syncthreads();
    if (tid == 0) {
      double m = -1e300;
      for (int e = 0; e < NEXP; ++e) m = fmax(m, sm.r.nv64[e]);
      m64s = m;
    }
    __syncthreads();
    if (tid < NEXP) sm.r.pe64[tid] = exp(sm.r.nv64[tid] - m64s);
    __syncthreads();
    if (tid == 0) {
      double ssum = 0.0;
      for (int e = 0; e < NEXP; ++e) ssum += sm.r.pe64[e];
      float* srow = out_s + (size_t)token * NEXP;
      for (int e = 0; e < NEXP; ++e) srow[e] = (float)(sm.r.pe64[e] / ssum);
      unsigned long long taken = 0ull;
      double pv[8]; int pi[8]; double wsum = 0.0;
#pragma unroll
      for (int p = 0; p < 8; ++p) {
        double best = -1e300; int bi = 0;
        for (int e = 0; e < NEXP; ++e) {
          const double v = sm.r.nv64[e];
          const bool cnd = (v > best) && (((taken >> e) & 1ull) == 0ull);
          best = cnd ? v : best;
          bi   = cnd ? e : bi;
        }
        taken |= (1ull << bi);
        pv[p] = sm.r.pe64[bi]; pi[p] = bi; wsum += pv[p];
      }
#pragma unroll
      for (int p = 0; p < 8; ++p) {
        out_w[(size_t)token * 8 + p] = (float)(pv[p] / wsum);
        out_i[(size_t)token * 8 + p] = (float)pi[p];
      }
    }
  }
}

extern "C" void kernel_launch(void* const* d_in, const int* in_sizes, int n_in,
                              void* d_out, int out_size, void* d_ws, size_t ws_size,
                              hipStream_t stream) {
  const float* x     = (const float*)d_in[0];
  const float* Wr    = (const float*)d_in[1];
  const float* br    = (const float*)d_in[2];
  const float* Wn    = (const float*)d_in[3];
  const float* bn    = (const float*)d_in[4];
  const float* noise = (const float*)d_in[5];

  const int M = in_sizes[0] / KDIM;             // 16384 tokens
  float* out   = (float*)d_out;
  float* out_w = out;                            // [M,8]
  float* out_i = out + (size_t)M * 8;            // [M,8] indices as float values
  float* out_s = out + (size_t)M * 16;           // [M,64]

  noisy_topk_router<<<dim3(M / BM), dim3(NTHREADS), 0, stream>>>(
      x, Wr, br, Wn, bn, noise, out_w, out_i, out_s);
}

// Round 7
// 234.891 us; speedup vs baseline: 1.2530x; 1.2530x over previous
//
#include <hip/hip_runtime.h>
#include <math.h>

// NoisyTopkRouter: B=4,S=4096,D=2048,E=64,TOP_K=8
// Split-precision bf16 MFMA GEMM (Ah*Bh + Ah*Bl + Al*Bh, err ~1e-5) +
// fused epilogue; near-tie tokens (gap < TAU) re-computed exactly in fp64.

#define KDIM 2048
#define NEXP 64
#define BM 32
#define BK 32
#define NTHREADS 256
#define NCHUNK (KDIM / BK)   // 64
#define LDT 40               // LDS tile row: 32 bf16 + 4 pad = 80B (16B-aligned)
#define LDSC 129
#define TAU 1.5e-4f

typedef __attribute__((ext_vector_type(8))) short short8v;
typedef __attribute__((ext_vector_type(4))) float f32x4;

__device__ __forceinline__ void bsplit(float v, ushort& h, ushort& l) {
  unsigned u = __float_as_uint(v);
  unsigned hu = (u + 0x8000u) & 0xFFFF0000u;   // bf16 round (half-away)
  h = (ushort)(hu >> 16);
  float r = v - __uint_as_float(hu);           // exact (Sterbenz zone)
  l = (ushort)((__float_as_uint(r) + 0x8000u) >> 16);
}

// one-time W split: Wh/Wl [128][2048] bf16 in d_ws (rows 0-63 route, 64-127 noise)
__global__ __launch_bounds__(256)
void convert_w(const float* __restrict__ Wr, const float* __restrict__ Wn,
               ushort* __restrict__ Wh, ushort* __restrict__ Wl) {
  const int g = blockIdx.x * 256 + threadIdx.x;    // 65536 threads, 4 elems each
  const int row = g >> 9;
  const int c4 = (g & 511) << 2;
  const float* src = (row < NEXP) ? (Wr + (size_t)row * KDIM + c4)
                                  : (Wn + (size_t)(row - NEXP) * KDIM + c4);
  const float4 v = *(const float4*)src;
  ushort4 h, l;
  bsplit(v.x, h.x, l.x); bsplit(v.y, h.y, l.y);
  bsplit(v.z, h.z, l.z); bsplit(v.w, h.w, l.w);
  *(ushort4*)(Wh + (size_t)row * KDIM + c4) = h;
  *(ushort4*)(Wl + (size_t)row * KDIM + c4) = l;
}

__global__ __launch_bounds__(NTHREADS, 4)
void router_mfma(const float* __restrict__ x,
                 const ushort* __restrict__ Wh, const ushort* __restrict__ Wl,
                 const float* __restrict__ Wr,  const float* __restrict__ Wn,
                 const float* __restrict__ br,  const float* __restrict__ bn,
                 const float* __restrict__ noise,
                 float* __restrict__ out_w, float* __restrict__ out_i,
                 float* __restrict__ out_s)
{
  union SM {
    struct {                                   // GEMM phase (double-buffered)
      ushort Ah[2][BM][LDT], Al[2][BM][LDT];   // 10 KB
      ushort Bh[2][128][LDT], Bl[2][128][LDT]; // 40 KB
    } g;
    float sc[BM][LDSC];                        // epilogue scores (16.5 KB)
    struct {                                   // fp64 refine
      float  xls[KDIM];
      double part[128][2];
      double nv64[NEXP];
      double pe64[NEXP];
    } r;
  };
  __shared__ SM sm;
  __shared__ int flagcnt;
  __shared__ int flaglist[BM];
  __shared__ double m64s;

  const int tid  = threadIdx.x;
  const int row0 = blockIdx.x * BM;
  if (tid == 0) flagcnt = 0;

  // staging maps
  const int ar = tid >> 3;                 // token row 0..31 (8 thr/row)
  const int ak = (tid & 7) << 2;           // k offset 0,4,...,28
  const float* xA = x + (size_t)(row0 + ar) * KDIM + ak;
  const int bp   = tid >> 7;               // 0=hi array, 1=lo array
  const int brow = tid & 127;              // W row 0..127
  const ushort* Wsrc = (bp ? Wl : Wh) + (size_t)brow * KDIM;

  // fragment maps: wave wid covers cols wid*32..wid*32+31, all 32 rows
  const int wid  = tid >> 6;
  const int lane = tid & 63;
  const int lr   = lane & 15;
  const int lg   = lane >> 4;

  f32x4 acc[2][2];
#pragma unroll
  for (int i = 0; i < 2; ++i)
#pragma unroll
    for (int j = 0; j < 2; ++j) acc[i][j] = (f32x4){0.f, 0.f, 0.f, 0.f};

  float4 av; uint4 bv0, bv1, bv2, bv3;

  // prologue: load + stage chunk 0 into buf 0
  av  = *(const float4*)(xA);
  bv0 = *(const uint4*)(Wsrc + 0);
  bv1 = *(const uint4*)(Wsrc + 8);
  bv2 = *(const uint4*)(Wsrc + 16);
  bv3 = *(const uint4*)(Wsrc + 24);
  {
    ushort4 h, l;
    bsplit(av.x, h.x, l.x); bsplit(av.y, h.y, l.y);
    bsplit(av.z, h.z, l.z); bsplit(av.w, h.w, l.w);
    *(ushort4*)&sm.g.Ah[0][ar][ak] = h;
    *(ushort4*)&sm.g.Al[0][ar][ak] = l;
    ushort (*Bd)[LDT] = bp ? sm.g.Bl[0] : sm.g.Bh[0];
    *(uint4*)&Bd[brow][0]  = bv0;
    *(uint4*)&Bd[brow][8]  = bv1;
    *(uint4*)&Bd[brow][16] = bv2;
    *(uint4*)&Bd[brow][24] = bv3;
  }

  for (int c = 0; c < NCHUNK; ++c) {
    const int cur = c & 1;
    __syncthreads();   // buf[cur] visible; buf[cur^1] readers (chunk c-1) done
    if (c + 1 < NCHUNK) {
      const int off = (c + 1) * BK;
      av  = *(const float4*)(xA + off);
      bv0 = *(const uint4*)(Wsrc + off);
      bv1 = *(const uint4*)(Wsrc + off + 8);
      bv2 = *(const uint4*)(Wsrc + off + 16);
      bv3 = *(const uint4*)(Wsrc + off + 24);
    }
    // fragments (16B LDS reads, 80B row stride -> bank-cycle floor)
    const short8v ah0 = *(const short8v*)&sm.g.Ah[cur][lr][lg * 8];
    const short8v ah1 = *(const short8v*)&sm.g.Ah[cur][16 + lr][lg * 8];
    const short8v al0 = *(const short8v*)&sm.g.Al[cur][lr][lg * 8];
    const short8v al1 = *(const short8v*)&sm.g.Al[cur][16 + lr][lg * 8];
    const int col0 = wid * 32 + lr;
    const short8v bh0 = *(const short8v*)&sm.g.Bh[cur][col0][lg * 8];
    const short8v bh1 = *(const short8v*)&sm.g.Bh[cur][col0 + 16][lg * 8];
    const short8v bl0 = *(const short8v*)&sm.g.Bl[cur][col0][lg * 8];
    const short8v bl1 = *(const short8v*)&sm.g.Bl[cur][col0 + 16][lg * 8];

    acc[0][0] = __builtin_amdgcn_mfma_f32_16x16x32_bf16(ah0, bh0, acc[0][0], 0, 0, 0);
    acc[0][1] = __builtin_amdgcn_mfma_f32_16x16x32_bf16(ah0, bh1, acc[0][1], 0, 0, 0);
    acc[1][0] = __builtin_amdgcn_mfma_f32_16x16x32_bf16(ah1, bh0, acc[1][0], 0, 0, 0);
    acc[1][1] = __builtin_amdgcn_mfma_f32_16x16x32_bf16(ah1, bh1, acc[1][1], 0, 0, 0);
    acc[0][0] = __builtin_amdgcn_mfma_f32_16x16x32_bf16(ah0, bl0, acc[0][0], 0, 0, 0);
    acc[0][1] = __builtin_amdgcn_mfma_f32_16x16x32_bf16(ah0, bl1, acc[0][1], 0, 0, 0);
    acc[1][0] = __builtin_amdgcn_mfma_f32_16x16x32_bf16(ah1, bl0, acc[1][0], 0, 0, 0);
    acc[1][1] = __builtin_amdgcn_mfma_f32_16x16x32_bf16(ah1, bl1, acc[1][1], 0, 0, 0);
    acc[0][0] = __builtin_amdgcn_mfma_f32_16x16x32_bf16(al0, bh0, acc[0][0], 0, 0, 0);
    acc[0][1] = __builtin_amdgcn_mfma_f32_16x16x32_bf16(al0, bh1, acc[0][1], 0, 0, 0);
    acc[1][0] = __builtin_amdgcn_mfma_f32_16x16x32_bf16(al1, bh0, acc[1][0], 0, 0, 0);
    acc[1][1] = __builtin_amdgcn_mfma_f32_16x16x32_bf16(al1, bh1, acc[1][1], 0, 0, 0);

    if (c + 1 < NCHUNK) {   // write next chunk into other buffer (no barrier needed)
      const int nxt = cur ^ 1;
      ushort4 h, l;
      bsplit(av.x, h.x, l.x); bsplit(av.y, h.y, l.y);
      bsplit(av.z, h.z, l.z); bsplit(av.w, h.w, l.w);
      *(ushort4*)&sm.g.Ah[nxt][ar][ak] = h;
      *(ushort4*)&sm.g.Al[nxt][ar][ak] = l;
      ushort (*Bd)[LDT] = bp ? sm.g.Bl[nxt] : sm.g.Bh[nxt];
      *(uint4*)&Bd[brow][0]  = bv0;
      *(uint4*)&Bd[brow][8]  = bv1;
      *(uint4*)&Bd[brow][16] = bv2;
      *(uint4*)&Bd[brow][24] = bv3;
    }
  }

  __syncthreads();   // all frag reads done; sc may alias tile memory
  // C layout (verified): col = lane&15, row = (lane>>4)*4 + reg
#pragma unroll
  for (int mf = 0; mf < 2; ++mf)
#pragma unroll
    for (int nf = 0; nf < 2; ++nf)
#pragma unroll
      for (int rr = 0; rr < 4; ++rr)
        sm.sc[mf * 16 + lg * 4 + rr][wid * 32 + nf * 16 + lr] = acc[mf][nf][rr];
  __syncthreads();

  // ---------------- fp32 epilogue + near-tie detection (proven) ----------------
  if (tid < BM) {
    const int t = tid;
    const int token = row0 + t;
    const float* nrow = noise + (size_t)token * NEXP;

    for (int e = 0; e < NEXP; ++e) {
      const float rte = sm.sc[t][e] + br[e];
      const float z   = sm.sc[t][e + NEXP] + bn[e];
      const float sp  = fmaxf(z, 0.f) + log1pf(expf(-fabsf(z)));
      sm.sc[t][e] = rte + nrow[e] * sp;
    }
    unsigned long long taken = 0ull;
    float vals9[9]; int idx9[9];
#pragma unroll
    for (int p = 0; p < 9; ++p) {
      float best = -INFINITY; int bi = 0;
      for (int e = 0; e < NEXP; ++e) {
        const float v = sm.sc[t][e];
        const bool cnd = (v > best) && (((taken >> e) & 1ull) == 0ull);
        best = cnd ? v : best;
        bi   = cnd ? e : bi;
      }
      taken |= (1ull << bi);
      vals9[p] = best; idx9[p] = bi;
    }
    bool flagged = false;
#pragma unroll
    for (int p = 0; p < 8; ++p) flagged |= (vals9[p] - vals9[p + 1] < TAU);

    if (flagged) {
      const int s = atomicAdd(&flagcnt, 1);
      flaglist[s] = t;
    } else {
      const float m = vals9[0];
      float ssum = 0.f;
      for (int e = 0; e < NEXP; ++e) {
        const float p = expf(sm.sc[t][e] - m);
        sm.sc[t][e] = p;
        ssum += p;
      }
      float* srow = out_s + (size_t)token * NEXP;
      for (int e = 0; e < NEXP; ++e) srow[e] = sm.sc[t][e] / ssum;
      float pt[8]; float wsum = 0.f;
#pragma unroll
      for (int p = 0; p < 8; ++p) { pt[p] = expf(vals9[p] - m); wsum += pt[p]; }
#pragma unroll
      for (int p = 0; p < 8; ++p) {
        out_w[(size_t)token * 8 + p] = pt[p] / wsum;
        out_i[(size_t)token * 8 + p] = (float)idx9[p];
      }
    }
  }
  __syncthreads();

  // ---------------- fp64 exact refine for flagged tokens (proven) ----------------
  const int nf = flagcnt;
  for (int i = 0; i < nf; ++i) {
    const int t = flaglist[i];
    const int token = row0 + t;
    __syncthreads();
    for (int k = tid * 8; k < KDIM; k += NTHREADS * 8) {
      *(float4*)&sm.r.xls[k]     = *(const float4*)&x[(size_t)token * KDIM + k];
      *(float4*)&sm.r.xls[k + 4] = *(const float4*)&x[(size_t)token * KDIM + k + 4];
    }
    __syncthreads();
    {
      const int e = tid & 127, h = tid >> 7;
      const float* Wrow = ((e < NEXP) ? (Wr + (size_t)e * KDIM)
                                      : (Wn + (size_t)(e - NEXP) * KDIM)) + h * 1024;
      const float* xh = sm.r.xls + h * 1024;
      double a0 = 0, a1 = 0, a2 = 0, a3 = 0;
      for (int k = 0; k < 1024; k += 4) {
        const float4 w4 = *(const float4*)&Wrow[k];
        const float4 x4 = *(const float4*)&xh[k];
        a0 = fma((double)x4.x, (double)w4.x, a0);
        a1 = fma((double)x4.y, (double)w4.y, a1);
        a2 = fma((double)x4.z, (double)w4.z, a2);
        a3 = fma((double)x4.w, (double)w4.w, a3);
      }
      sm.r.part[e][h] = (a0 + a1) + (a2 + a3);
    }
    __syncthreads();
    if (tid < NEXP) {
      const double rte = sm.r.part[tid][0] + sm.r.part[tid][1] + (double)br[tid];
      const double z   = sm.r.part[tid + NEXP][0] + sm.r.part[tid + NEXP][1] + (double)bn[tid];
      const double sp  = fmax(z, 0.0) + log1p(exp(-fabs(z)));
      sm.r.nv64[tid] = rte + (double)noise[(size_t)token * NEXP + tid] * sp;
    }
    __syncthreads();
    if (tid == 0) {
      double m = -1e300;
      for (int e = 0; e < NEXP; ++e) m = fmax(m, sm.r.nv64[e]);
      m64s = m;
    }
    __syncthreads();
    if (tid < NEXP) sm.r.pe64[tid] = exp(sm.r.nv64[tid] - m64s);
    __syncthreads();
    if (tid == 0) {
      double ssum = 0.0;
      for (int e = 0; e < NEXP; ++e) ssum += sm.r.pe64[e];
      float* srow = out_s + (size_t)token * NEXP;
      for (int e = 0; e < NEXP; ++e) srow[e] = (float)(sm.r.pe64[e] / ssum);
      unsigned long long taken = 0ull;
      double pv[8]; int pi[8]; double wsum = 0.0;
#pragma unroll
      for (int p = 0; p < 8; ++p) {
        double best = -1e300; int bi = 0;
        for (int e = 0; e < NEXP; ++e) {
          const double v = sm.r.nv64[e];
          const bool cnd = (v > best) && (((taken >> e) & 1ull) == 0ull);
          best = cnd ? v : best;
          bi   = cnd ? e : bi;
        }
        taken |= (1ull << bi);
        pv[p] = sm.r.pe64[bi]; pi[p] = bi; wsum += pv[p];
      }
#pragma unroll
      for (int p = 0; p < 8; ++p) {
        out_w[(size_t)token * 8 + p] = (float)(pv[p] / wsum);
        out_i[(size_t)token * 8 + p] = (float)pi[p];
      }
    }
  }
}

extern "C" void kernel_launch(void* const* d_in, const int* in_sizes, int n_in,
                              void* d_out, int out_size, void* d_ws, size_t ws_size,
                              hipStream_t stream) {
  const float* x     = (const float*)d_in[0];
  const float* Wr    = (const float*)d_in[1];
  const float* br    = (const float*)d_in[2];
  const float* Wn    = (const float*)d_in[3];
  const float* bn    = (const float*)d_in[4];
  const float* noise = (const float*)d_in[5];

  const int M = in_sizes[0] / KDIM;             // 16384 tokens
  ushort* Wh = (ushort*)d_ws;                   // [128][2048] bf16 hi
  ushort* Wl = Wh + (size_t)128 * KDIM;         // [128][2048] bf16 lo (1 MB total)

  float* out   = (float*)d_out;
  float* out_w = out;                            // [M,8]
  float* out_i = out + (size_t)M * 8;            // [M,8] indices as float values
  float* out_s = out + (size_t)M * 16;           // [M,64]

  convert_w<<<dim3(256), dim3(256), 0, stream>>>(Wr, Wn, Wh, Wl);
  router_mfma<<<dim3(M / BM), dim3(NTHREADS), 0, stream>>>(
      x, Wh, Wl, Wr, Wn, br, bn, noise, out_w, out_i, out_s);
}